// Round 1
// baseline (53.143 us; speedup 1.0000x reference)
//
#include <hip/hip_runtime.h>
#include <hip/hip_bf16.h>
#include <math.h>
#include <limits.h>

// Problem constants (fixed by setup_inputs)
#define S_STAGES 2
#define B_DIM 8
#define J_DIM 17
#define ROWS_PER_STAGE (B_DIM * J_DIM)          // 136
#define N_ROWS (S_STAGES * ROWS_PER_STAGE)      // 272
#define XD 64
#define ROW_N (XD * XD * XD)                    // 262144 floats per row
#define CHUNKS_PER_ROW 16
#define N_BLOCKS1 (N_ROWS * CHUNKS_PER_ROW)     // 4352 = 17 * 256 -> perfect CU balance
#define CHUNK_FLOATS (ROW_N / CHUNKS_PER_ROW)   // 16384 floats = 4096 float4
#define BETA_C 0.01f
#define EPS_C 1e-6f

// Kernel 1: per-(row, chunk) online logsumexp partial -> (m, s) pair in ws.
__global__ __launch_bounds__(256) void lse_partial_kernel(
    const float* __restrict__ vol, float2* __restrict__ partials) {
  const int blk = blockIdx.x;              // 0..4351
  const int row = blk >> 4;                // /16
  const int c   = blk & 15;
  const float4* __restrict__ p = reinterpret_cast<const float4*>(
      vol + (size_t)row * ROW_N + (size_t)c * CHUNK_FLOATS);
  const int t = threadIdx.x;

  float m = -INFINITY;
  float ssum = 0.0f;
  // 4096 float4 / 256 threads = 16 iterations, fully coalesced
  #pragma unroll
  for (int i = 0; i < 16; ++i) {
    float4 v = p[t + i * 256];
    float m01 = fmaxf(v.x, v.y);
    float m23 = fmaxf(v.z, v.w);
    float m4  = fmaxf(m01, m23);
    float nm  = fmaxf(m, m4);
    ssum = ssum * __expf(m - nm)
         + __expf(v.x - nm) + __expf(v.y - nm)
         + __expf(v.z - nm) + __expf(v.w - nm);
    m = nm;
  }

  // wave-64 butterfly combine of (m, s)
  #pragma unroll
  for (int off = 32; off > 0; off >>= 1) {
    float m2 = __shfl_xor(m, off, 64);
    float s2 = __shfl_xor(ssum, off, 64);
    float nm = fmaxf(m, m2);
    ssum = ssum * __expf(m - nm) + s2 * __expf(m2 - nm);
    m = nm;
  }

  __shared__ float sm[4];
  __shared__ float ss[4];
  const int wave = t >> 6;
  if ((t & 63) == 0) { sm[wave] = m; ss[wave] = ssum; }
  __syncthreads();
  if (t == 0) {
    float M = sm[0], Ssum = ss[0];
    #pragma unroll
    for (int w = 1; w < 4; ++w) {
      float nm = fmaxf(M, sm[w]);
      Ssum = Ssum * __expf(M - nm) + ss[w] * __expf(sm[w] - nm);
      M = nm;
    }
    partials[blk] = make_float2(M, Ssum);
  }
}

// Kernel 2: single block. Merge partials per row, gather logit, per-stage
// bound check + deterministic final reduction.
__global__ __launch_bounds__(512) void finalize_kernel(
    const float* __restrict__ vol,
    const float* __restrict__ label,      // [B, J, 3]
    const float* __restrict__ vmax_cat,   // [B, S, 3]
    const float* __restrict__ vmin_cat,   // [B, S, 3]
    const float2* __restrict__ partials,  // [N_ROWS * CHUNKS_PER_ROW]
    float* __restrict__ out) {
  __shared__ float terms[N_ROWS];
  __shared__ int s_min[S_STAGES];
  __shared__ int s_max[S_STAGES];

  const int t = threadIdx.x;
  if (t < S_STAGES) { s_min[t] = INT_MAX; s_max[t] = INT_MIN; }
  __syncthreads();

  if (t < N_ROWS) {
    const int row = t;
    const int s   = row / ROWS_PER_STAGE;
    const int rr  = row % ROWS_PER_STAGE;
    const int b   = rr / J_DIM;
    const int j   = rr % J_DIM;

    // merge the row's 16 partials
    float M = -INFINITY, Ssum = 0.0f;
    #pragma unroll
    for (int k = 0; k < CHUNKS_PER_ROW; ++k) {
      float2 ps = partials[row * CHUNKS_PER_ROW + k];
      float nm = fmaxf(M, ps.x);
      Ssum = Ssum * expf(M - nm) + ps.y * expf(ps.x - nm);
      M = nm;
    }
    const float lse = M + logf(Ssum);

    // index computation — identical fp32 op sequence as the reference
    int idx3[3];
    int mn = INT_MAX, mx = INT_MIN;
    #pragma unroll
    for (int k = 0; k < 3; ++k) {
      float lab  = label[((b * J_DIM) + j) * 3 + k];
      float vmax = vmax_cat[(b * S_STAGES + s) * 3 + k];
      float vmin = vmin_cat[(b * S_STAGES + s) * 3 + k];
      float mean  = (vmax + vmin) * 0.5f;
      float scale = (vmax - vmin) * 0.5f;
      float g = (lab - mean) / scale;
      float tt = ((g + 1.0f) * 0.5f) * (float)(XD - 1);
      int idx = (int)floorf(tt);
      idx3[k] = idx;
      mn = min(mn, idx);
      mx = max(mx, idx);
    }
    atomicMin(&s_min[s], mn);
    atomicMax(&s_max[s], mx);

    const int flat = idx3[0] * (XD * XD) + idx3[1] * XD + idx3[2];
    const float logit = vol[(size_t)row * ROW_N + flat];
    terms[row] = -logf(expf(logit - lse) + EPS_C);
  }
  __syncthreads();

  if (t == 0) {
    float total = 0.0f;
    for (int s = 0; s < S_STAGES; ++s) {
      float acc = 0.0f;
      for (int r = 0; r < ROWS_PER_STAGE; ++r)
        acc += terms[s * ROWS_PER_STAGE + r];
      const int mx = s_max[s], mn = s_min[s];
      const bool in_bound = (mx < XD) && (mx > 0) && (mn < XD) && (mn > 0);
      if (in_bound) total += (BETA_C * acc) / (float)ROWS_PER_STAGE;
    }
    out[0] = total;
  }
}

extern "C" void kernel_launch(void* const* d_in, const int* in_sizes, int n_in,
                              void* d_out, int out_size, void* d_ws, size_t ws_size,
                              hipStream_t stream) {
  const float* volumes  = (const float*)d_in[0];
  const float* label    = (const float*)d_in[1];
  const float* vmax_cat = (const float*)d_in[2];
  const float* vmin_cat = (const float*)d_in[3];
  float* out = (float*)d_out;
  float2* partials = (float2*)d_ws;   // needs N_BLOCKS1 * 8 = 34816 bytes

  lse_partial_kernel<<<N_BLOCKS1, 256, 0, stream>>>(volumes, partials);
  finalize_kernel<<<1, 512, 0, stream>>>(volumes, label, vmax_cat, vmin_cat,
                                         partials, out);
}